// Round 1
// baseline (4624.802 us; speedup 1.0000x reference)
//
#include <hip/hip_runtime.h>
#include <cstdint>
#include <cstddef>

typedef __attribute__((ext_vector_type(8))) short short8;
typedef __attribute__((ext_vector_type(4))) short short4v;
typedef __attribute__((ext_vector_type(4))) float f32x4;

#define DEV __device__ __forceinline__

// Problem geometry (fixed by the reference)
constexpr int DD = 2048;           // D
constexpr int HHID = 8192;         // H
constexpr int BB = 4;              // B
constexpr int SS = 2048;           // S
constexpr size_t NX = (size_t)BB * SS * DD;   // 16,777,216  (x / Q / K / V element count)
constexpr size_t NW = (size_t)DD * HHID;      // 16,777,216  (weight element count)
constexpr size_t NH = (size_t)BB * SS * HHID; // 67,108,864  (hidden element count)

// Scratch layout (bytes)
constexpr size_t OFF_XH = 0;
constexpr size_t OFF_XL = OFF_XH + NX * 2;
constexpr size_t OFF_WH = OFF_XL + NX * 2;
constexpr size_t OFF_WL = OFF_WH + NW * 2;
constexpr size_t OFF_HH = OFF_WL + NW * 2;   // 128 MiB region (bf16 hidden hi / reused)
constexpr size_t OFF_HL = OFF_HH + NH * 2;   // 128 MiB region (bf16 hidden lo / reused)
constexpr size_t OFF_QH = OFF_HL + NH * 2;
constexpr size_t OFF_QL = OFF_QH + NX * 2;
constexpr size_t OFF_KH = OFF_QL + NX * 2;
constexpr size_t OFF_KL = OFF_KH + NX * 2;
constexpr size_t OFF_V  = OFF_KL + NX * 2;
constexpr size_t WS_TOTAL = OFF_V + NX * 2;  // ~570 MB
// Aliases (lifetimes are disjoint from h / hv usage)
constexpr size_t OFF_ST = OFF_HH;            // fp32 scores^T  (67 MB <= 128 MB region)
constexpr size_t OFF_PT = OFF_HL;            // bf16 probs^T   (33 MB <= 128 MB region)

__device__ __align__(256) unsigned char g_ws[WS_TOTAL];

DEV unsigned char* wsbase(unsigned char* p) { return p ? p : (unsigned char*)g_ws; }
DEV short f2bf(float v) { __bf16 b = (__bf16)v; return __builtin_bit_cast(short, b); }
DEV float bf2f(short s) { return (float)__builtin_bit_cast(__bf16, s); }

DEV void gl16(const short* g, short* l) {
  __builtin_amdgcn_global_load_lds((const __attribute__((address_space(1))) void*)g,
                                   (__attribute__((address_space(3))) void*)l, 16, 0, 0);
}

// ---------------------------------------------------------------------------
// split cast: fp32 -> (hi, lo) bf16, elementwise, vectorized
// ---------------------------------------------------------------------------
__global__ void split_cast_k(const float* __restrict__ x, unsigned char* wsb,
                             size_t oh, size_t ol, size_t n4) {
  unsigned char* ws = wsbase(wsb);
  short4v* OH = (short4v*)(ws + oh);
  short4v* OL = (short4v*)(ws + ol);
  const f32x4* X = (const f32x4*)x;
  for (size_t i = (size_t)blockIdx.x * blockDim.x + threadIdx.x; i < n4;
       i += (size_t)gridDim.x * blockDim.x) {
    const f32x4 v = X[i];
    short4v hs, ls;
#pragma unroll
    for (int e = 0; e < 4; ++e) {
      const short hb = f2bf(v[e]);
      hs[e] = hb;
      ls[e] = f2bf(v[e] - bf2f(hb));
    }
    OH[i] = hs;
    OL[i] = ls;
  }
}

// ---------------------------------------------------------------------------
// transpose + (split-)cast: src R x C fp32 (row-major) -> out C x R bf16 hi[/lo]
// ---------------------------------------------------------------------------
__global__ void transpose_cast_k(const float* __restrict__ src, unsigned char* wsb,
                                 size_t oh, size_t ol, int R, int C, int do_split) {
  __shared__ float t[32][33];
  unsigned char* ws = wsbase(wsb);
  short* OH = (short*)(ws + oh);
  short* OL = (short*)(ws + ol);
  const int c0 = blockIdx.x << 5, r0 = blockIdx.y << 5;
  const int x = threadIdx.x, y = threadIdx.y;
#pragma unroll
  for (int i = 0; i < 4; ++i) {
    const int rr = y + (i << 3);
    t[rr][x] = src[(size_t)(r0 + rr) * C + c0 + x];
  }
  __syncthreads();
#pragma unroll
  for (int i = 0; i < 4; ++i) {
    const int oc = y + (i << 3);
    const float v = t[x][oc];
    const size_t o = (size_t)(c0 + oc) * R + r0 + x;
    const short hb = f2bf(v);
    OH[o] = hb;
    if (do_split) OL[o] = f2bf(v - bf2f(hb));
  }
}

// ---------------------------------------------------------------------------
// GEMM: C[m][n] = sum_k A[m][k] * BT[n][k]  (A: MxK rm, BT: NxK rm, bf16 scratch)
// NA/NB = 1 (plain) or 2 (hi+lo split, 3 MFMAs: hh + hl + lh)
// STORE: 0 = bias(+relu) -> split bf16 (ooff0/ooff1)
//        1 = bias(+relu) -> bf16 (ooff0)
//        2 = fp32 TRANSPOSED scratch store out[n*M+m]  (scores^T), batched
//        3 = fp32 -> optr normal row-major, batched
// ---------------------------------------------------------------------------
template <int NA, int NB, bool RELU, int STORE>
__launch_bounds__(256, 2)
__global__ void gemm_k(unsigned char* wsb,
                       size_t aoff0, size_t aoff1, size_t boff0, size_t boff1,
                       const float* __restrict__ bias,
                       size_t ooff0, size_t ooff1, float* __restrict__ optr,
                       int M, int N, int K) {
  unsigned char* ws = wsbase(wsb);
  const int tid = threadIdx.x;
  const int lane = tid & 63;
  const int wave = tid >> 6;
  const int wm = (wave >> 1) << 6;   // wave row offset within 128-tile
  const int wn = (wave & 1) << 6;    // wave col offset
  const int bz = blockIdx.z;
  const size_t batchA = (size_t)bz * M * K;
  const size_t batchB = (size_t)bz * N * K;
  const int brow = blockIdx.y << 7;
  const int bcol = blockIdx.x << 7;

  const short* A0 = (const short*)(ws + aoff0) + batchA;
  const short* A1 = (const short*)(ws + aoff1) + batchA;
  const short* B0 = (const short*)(ws + boff0) + batchB;
  const short* B1 = (const short*)(ws + boff1) + batchB;

  __shared__ alignas(16) short As[NA][128 * 32];
  __shared__ alignas(16) short Bs[NB][128 * 32];

  f32x4 acc[4][4] = {};

  // staging: thread t loads 16B at lds short-offset t*8 and (t+256)*8 (linear in lane)
  const int sr = tid >> 2;             // row 0..63
  const int sk = (tid & 3) << 3;       // k sub-offset 0,8,16,24
  size_t gA0 = (size_t)(brow + sr) * K + sk;
  size_t gA1 = gA0 + (size_t)64 * K;
  size_t gB0 = (size_t)(bcol + sr) * K + sk;
  size_t gB1 = gB0 + (size_t)64 * K;
  const int l0 = tid << 3;
  const int l1 = (tid + 256) << 3;

  const int fr = lane & 15;
  const int fko = (lane >> 4) << 3;

  for (int k0 = 0; k0 < K; k0 += 32) {
    gl16(A0 + gA0, &As[0][l0]);
    gl16(A0 + gA1, &As[0][l1]);
    if constexpr (NA == 2) { gl16(A1 + gA0, &As[1][l0]); gl16(A1 + gA1, &As[1][l1]); }
    gl16(B0 + gB0, &Bs[0][l0]);
    gl16(B0 + gB1, &Bs[0][l1]);
    if constexpr (NB == 2) { gl16(B1 + gB0, &Bs[1][l0]); gl16(B1 + gB1, &Bs[1][l1]); }
    gA0 += 32; gA1 += 32; gB0 += 32; gB1 += 32;
    __syncthreads();   // drains vmcnt (global_load_lds) + lgkm

    short8 a0[4], b0[4], a1[4], b1[4];
#pragma unroll
    for (int i = 0; i < 4; ++i) {
      a0[i] = *(const short8*)&As[0][(wm + i * 16 + fr) * 32 + fko];
      b0[i] = *(const short8*)&Bs[0][(wn + i * 16 + fr) * 32 + fko];
      if constexpr (NA == 2) a1[i] = *(const short8*)&As[1][(wm + i * 16 + fr) * 32 + fko];
      if constexpr (NB == 2) b1[i] = *(const short8*)&Bs[1][(wn + i * 16 + fr) * 32 + fko];
    }
#pragma unroll
    for (int i = 0; i < 4; ++i)
#pragma unroll
      for (int j = 0; j < 4; ++j) {
        acc[i][j] = __builtin_amdgcn_mfma_f32_16x16x32_bf16(a0[i], b0[j], acc[i][j], 0, 0, 0);
        if constexpr (NB == 2)
          acc[i][j] = __builtin_amdgcn_mfma_f32_16x16x32_bf16(a0[i], b1[j], acc[i][j], 0, 0, 0);
        if constexpr (NA == 2)
          acc[i][j] = __builtin_amdgcn_mfma_f32_16x16x32_bf16(a1[i], b0[j], acc[i][j], 0, 0, 0);
      }
    __syncthreads();
  }

  // epilogue
  short* Oh = (short*)(ws + ooff0);
  short* Ol = (short*)(ws + ooff1);
  float* Of = (float*)(ws + ooff0) + (size_t)bz * M * N;
  float* Op = optr + (size_t)bz * M * N;
  const int fq4 = (lane >> 4) << 2;
#pragma unroll
  for (int i = 0; i < 4; ++i) {
    const int r = brow + wm + i * 16 + fq4;
#pragma unroll
    for (int j = 0; j < 4; ++j) {
      const int c = bcol + wn + j * 16 + fr;
      const float bv = bias ? bias[c] : 0.0f;
#pragma unroll
      for (int e = 0; e < 4; ++e) {
        float u = acc[i][j][e] + bv;
        if constexpr (RELU) u = fmaxf(u, 0.0f);
        const size_t ro = (size_t)(r + e);
        if constexpr (STORE == 0) {
          const short hb = f2bf(u);
          Oh[ro * N + c] = hb;
          Ol[ro * N + c] = f2bf(u - bf2f(hb));
        } else if constexpr (STORE == 1) {
          Oh[ro * N + c] = f2bf(u);
        } else if constexpr (STORE == 2) {
          Of[(size_t)c * M + ro] = u;   // transposed: ST[n][m]
        } else {
          Op[ro * N + c] = u;
        }
      }
    }
  }
}

// ---------------------------------------------------------------------------
// row softmax over ST rows (axis-1 softmax of scores), output bf16 probs^T
// ---------------------------------------------------------------------------
__launch_bounds__(256)
__global__ void softmax_rows_k(unsigned char* wsb, size_t st, size_t pt) {
  constexpr int S = 2048;
  unsigned char* ws = wsbase(wsb);
  const f32x4* row = (const f32x4*)((const float*)(ws + st) + (size_t)blockIdx.x * S);
  short4v* out = (short4v*)((short*)(ws + pt) + (size_t)blockIdx.x * S);
  const int tid = threadIdx.x, lane = tid & 63, wv = tid >> 6;
  const f32x4 a = row[tid];
  const f32x4 b = row[tid + 256];
  float m = fmaxf(fmaxf(fmaxf(a[0], a[1]), fmaxf(a[2], a[3])),
                  fmaxf(fmaxf(b[0], b[1]), fmaxf(b[2], b[3])));
#pragma unroll
  for (int o = 32; o; o >>= 1) m = fmaxf(m, __shfl_xor(m, o));
  __shared__ float rb[8];
  if (lane == 0) rb[wv] = m;
  __syncthreads();
  m = fmaxf(fmaxf(rb[0], rb[1]), fmaxf(rb[2], rb[3]));
  float e[8];
  float s = 0.0f;
#pragma unroll
  for (int q = 0; q < 4; ++q) { e[q] = expf(a[q] - m); s += e[q]; }
#pragma unroll
  for (int q = 0; q < 4; ++q) { e[4 + q] = expf(b[q] - m); s += e[4 + q]; }
#pragma unroll
  for (int o = 32; o; o >>= 1) s += __shfl_xor(s, o);
  if (lane == 0) rb[4 + wv] = s;
  __syncthreads();
  s = rb[4] + rb[5] + rb[6] + rb[7];
  const float inv = 1.0f / s;
  short4v o1, o2;
#pragma unroll
  for (int q = 0; q < 4; ++q) { o1[q] = f2bf(e[q] * inv); o2[q] = f2bf(e[4 + q] * inv); }
  out[tid] = o1;
  out[tid + 256] = o2;
}

// ---------------------------------------------------------------------------
extern "C" void kernel_launch(void* const* d_in, const int* in_sizes, int n_in,
                              void* d_out, int out_size, void* d_ws, size_t ws_size,
                              hipStream_t stream) {
  const float* x   = (const float*)d_in[0];
  const float* qw1 = (const float*)d_in[1];
  const float* qb1 = (const float*)d_in[2];
  const float* qw2 = (const float*)d_in[3];
  const float* qb2 = (const float*)d_in[4];
  const float* kw1 = (const float*)d_in[5];
  const float* kb1 = (const float*)d_in[6];
  const float* kw2 = (const float*)d_in[7];
  const float* kb2 = (const float*)d_in[8];
  const float* vw1 = (const float*)d_in[9];
  const float* vb1 = (const float*)d_in[10];
  const float* vw2 = (const float*)d_in[11];
  const float* vb2 = (const float*)d_in[12];
  float* out = (float*)d_out;
  unsigned char* wsb = (ws_size >= WS_TOTAL) ? (unsigned char*)d_ws : nullptr;

  const int M = BB * SS;  // 8192 rows for the MLP GEMMs
  dim3 blk(256);
  dim3 tb(32, 8);

  // x -> hi/lo bf16
  split_cast_k<<<4096, 256, 0, stream>>>(x, wsb, OFF_XH, OFF_XL, NX / 4);

  // ---- Q path (split precision) ----
  transpose_cast_k<<<dim3(HHID / 32, DD / 32), tb, 0, stream>>>(qw1, wsb, OFF_WH, OFF_WL, DD, HHID, 1);
  gemm_k<2, 2, true, 0><<<dim3(64, 64, 1), blk, 0, stream>>>(
      wsb, OFF_XH, OFF_XL, OFF_WH, OFF_WL, qb1, OFF_HH, OFF_HL, nullptr, M, HHID, DD);
  transpose_cast_k<<<dim3(DD / 32, HHID / 32), tb, 0, stream>>>(qw2, wsb, OFF_WH, OFF_WL, HHID, DD, 1);
  gemm_k<2, 2, false, 0><<<dim3(16, 64, 1), blk, 0, stream>>>(
      wsb, OFF_HH, OFF_HL, OFF_WH, OFF_WL, qb2, OFF_QH, OFF_QL, nullptr, M, DD, HHID);

  // ---- K path (split precision) ----
  transpose_cast_k<<<dim3(HHID / 32, DD / 32), tb, 0, stream>>>(kw1, wsb, OFF_WH, OFF_WL, DD, HHID, 1);
  gemm_k<2, 2, true, 0><<<dim3(64, 64, 1), blk, 0, stream>>>(
      wsb, OFF_XH, OFF_XL, OFF_WH, OFF_WL, kb1, OFF_HH, OFF_HL, nullptr, M, HHID, DD);
  transpose_cast_k<<<dim3(DD / 32, HHID / 32), tb, 0, stream>>>(kw2, wsb, OFF_WH, OFF_WL, HHID, DD, 1);
  gemm_k<2, 2, false, 0><<<dim3(16, 64, 1), blk, 0, stream>>>(
      wsb, OFF_HH, OFF_HL, OFF_WH, OFF_WL, kb2, OFF_KH, OFF_KL, nullptr, M, DD, HHID);

  // ---- V path (plain bf16) ----
  transpose_cast_k<<<dim3(HHID / 32, DD / 32), tb, 0, stream>>>(vw1, wsb, OFF_WH, OFF_WL, DD, HHID, 0);
  gemm_k<1, 1, true, 1><<<dim3(64, 64, 1), blk, 0, stream>>>(
      wsb, OFF_XH, 0, OFF_WH, 0, vb1, OFF_HH, 0, nullptr, M, HHID, DD);
  transpose_cast_k<<<dim3(DD / 32, HHID / 32), tb, 0, stream>>>(vw2, wsb, OFF_WH, OFF_WL, HHID, DD, 0);
  gemm_k<1, 1, false, 1><<<dim3(16, 64, 1), blk, 0, stream>>>(
      wsb, OFF_HH, 0, OFF_WH, 0, vb2, OFF_V, 0, nullptr, M, DD, HHID);

  // ---- scores^T = (Q K^T)^T per batch, split precision, fp32 ----
  gemm_k<2, 2, false, 2><<<dim3(16, 16, BB), blk, 0, stream>>>(
      wsb, OFF_QH, OFF_QL, OFF_KH, OFF_KL, nullptr, OFF_ST, 0, nullptr, SS, SS, DD);

  // ---- softmax over axis 1 == row softmax of ST; writes bf16 probs^T ----
  softmax_rows_k<<<BB * SS, 256, 0, stream>>>(wsb, OFF_ST, OFF_PT);

  // ---- out = V @ probs  (B^T = probs^T), fp32 to d_out ----
  gemm_k<1, 1, false, 3><<<dim3(16, 16, BB), blk, 0, stream>>>(
      wsb, OFF_V, 0, OFF_PT, 0, nullptr, 0, 0, out, SS, SS, DD);
}

// Round 2
// 3522.775 us; speedup vs baseline: 1.3128x; 1.3128x over previous
//
#include <hip/hip_runtime.h>
#include <cstdint>
#include <cstddef>

typedef __attribute__((ext_vector_type(8))) short short8;
typedef __attribute__((ext_vector_type(4))) short short4v;
typedef __attribute__((ext_vector_type(4))) float f32x4;

#define DEV __device__ __forceinline__

// Problem geometry (fixed by the reference)
constexpr int DD = 2048;           // D
constexpr int HHID = 8192;         // H
constexpr int BB = 4;              // B
constexpr int SS = 2048;           // S
constexpr size_t NX = (size_t)BB * SS * DD;   // 16,777,216
constexpr size_t NW = (size_t)DD * HHID;      // 16,777,216
constexpr size_t NH = (size_t)BB * SS * HHID; // 67,108,864

// Scratch layout (bytes)
constexpr size_t OFF_XH = 0;
constexpr size_t OFF_XL = OFF_XH + NX * 2;
constexpr size_t OFF_WH = OFF_XL + NX * 2;
constexpr size_t OFF_WL = OFF_WH + NW * 2;
constexpr size_t OFF_HH = OFF_WL + NW * 2;   // 128 MiB region
constexpr size_t OFF_HL = OFF_HH + NH * 2;   // 128 MiB region
constexpr size_t OFF_QH = OFF_HL + NH * 2;
constexpr size_t OFF_QL = OFF_QH + NX * 2;
constexpr size_t OFF_KH = OFF_QL + NX * 2;
constexpr size_t OFF_KL = OFF_KH + NX * 2;
constexpr size_t OFF_V  = OFF_KL + NX * 2;
constexpr size_t WS_TOTAL = OFF_V + NX * 2;  // ~570 MB
constexpr size_t OFF_ST = OFF_HH;            // fp32 scores^T
constexpr size_t OFF_PT = OFF_HL;            // bf16 probs^T

__device__ __align__(256) unsigned char g_ws[WS_TOTAL];

DEV unsigned char* wsbase(unsigned char* p) { return p ? p : (unsigned char*)g_ws; }
DEV short f2bf(float v) { __bf16 b = (__bf16)v; return __builtin_bit_cast(short, b); }
DEV float bf2f(short s) { return (float)__builtin_bit_cast(__bf16, s); }

DEV void gl16(const short* g, short* l) {
  __builtin_amdgcn_global_load_lds((const __attribute__((address_space(1))) void*)g,
                                   (__attribute__((address_space(3))) void*)l, 16, 0, 0);
}

// ---------------------------------------------------------------------------
// split cast: fp32 -> (hi, lo) bf16
// ---------------------------------------------------------------------------
__global__ void split_cast_k(const float* __restrict__ x, unsigned char* wsb,
                             size_t oh, size_t ol, size_t n4) {
  unsigned char* ws = wsbase(wsb);
  short4v* OH = (short4v*)(ws + oh);
  short4v* OL = (short4v*)(ws + ol);
  const f32x4* X = (const f32x4*)x;
  for (size_t i = (size_t)blockIdx.x * blockDim.x + threadIdx.x; i < n4;
       i += (size_t)gridDim.x * blockDim.x) {
    const f32x4 v = X[i];
    short4v hs, ls;
#pragma unroll
    for (int e = 0; e < 4; ++e) {
      const short hb = f2bf(v[e]);
      hs[e] = hb;
      ls[e] = f2bf(v[e] - bf2f(hb));
    }
    OH[i] = hs;
    OL[i] = ls;
  }
}

// ---------------------------------------------------------------------------
// transpose + (split-)cast: src R x C fp32 -> out C x R bf16 hi[/lo]
// ---------------------------------------------------------------------------
__global__ void transpose_cast_k(const float* __restrict__ src, unsigned char* wsb,
                                 size_t oh, size_t ol, int R, int C, int do_split) {
  __shared__ float t[32][33];
  unsigned char* ws = wsbase(wsb);
  short* OH = (short*)(ws + oh);
  short* OL = (short*)(ws + ol);
  const int c0 = blockIdx.x << 5, r0 = blockIdx.y << 5;
  const int x = threadIdx.x, y = threadIdx.y;
#pragma unroll
  for (int i = 0; i < 4; ++i) {
    const int rr = y + (i << 3);
    t[rr][x] = src[(size_t)(r0 + rr) * C + c0 + x];
  }
  __syncthreads();
#pragma unroll
  for (int i = 0; i < 4; ++i) {
    const int oc = y + (i << 3);
    const float v = t[x][oc];
    const size_t o = (size_t)(c0 + oc) * R + r0 + x;
    const short hb = f2bf(v);
    OH[o] = hb;
    if (do_split) OL[o] = f2bf(v - bf2f(hb));
  }
}

// ---------------------------------------------------------------------------
// 256x256-tile 8-wave deep-pipelined GEMM (4 phases / K-tile, counted vmcnt).
// C[m][n] = sum_k A[m][k] * BT[n][k].  NAB=1: plain bf16, BK=64.
// NAB=2: split hi/lo bf16 (3 MFMA terms), BK=32.
// STORE: 0 split-bf16 out, 1 bf16 out, 2 fp32 transposed scratch, 3 fp32 optr.
// ---------------------------------------------------------------------------
constexpr int CH = 8192;        // shorts per 16KB chunk
constexpr int BUF = 4 * CH;     // shorts per 64KB buffer

template <int NAB>
DEV short8 read_frag(const short* bufp, int regionBase, int row, int s, int fg) {
  if constexpr (NAB == 1) {
    return *(const short8*)&bufp[regionBase + row * 64 + ((((s << 2) | fg) ^ (row & 7)) << 3)];
  } else {
    return *(const short8*)&bufp[regionBase + s * CH + row * 32 + ((fg ^ ((row >> 1) & 3)) << 3)];
  }
}

template <int NAB, int P>
DEV void mfma_cluster(f32x4 (&acc)[8][4], short8 (&av)[2][2], short8 (&bfr)[4][2]) {
  if constexpr (NAB == 1) {
#pragma unroll
    for (int s = 0; s < 2; ++s)
#pragma unroll
      for (int i2 = 0; i2 < 2; ++i2)
#pragma unroll
        for (int j = 0; j < 4; ++j)
          acc[2 * P + i2][j] = __builtin_amdgcn_mfma_f32_16x16x32_bf16(
              av[i2][s], bfr[j][s], acc[2 * P + i2][j], 0, 0, 0);
  } else {
#pragma unroll
    for (int i2 = 0; i2 < 2; ++i2)
#pragma unroll
      for (int j = 0; j < 4; ++j)
        acc[2 * P + i2][j] = __builtin_amdgcn_mfma_f32_16x16x32_bf16(
            av[i2][0], bfr[j][0], acc[2 * P + i2][j], 0, 0, 0);
#pragma unroll
    for (int i2 = 0; i2 < 2; ++i2)
#pragma unroll
      for (int j = 0; j < 4; ++j)
        acc[2 * P + i2][j] = __builtin_amdgcn_mfma_f32_16x16x32_bf16(
            av[i2][0], bfr[j][1], acc[2 * P + i2][j], 0, 0, 0);
#pragma unroll
    for (int i2 = 0; i2 < 2; ++i2)
#pragma unroll
      for (int j = 0; j < 4; ++j)
        acc[2 * P + i2][j] = __builtin_amdgcn_mfma_f32_16x16x32_bf16(
            av[i2][1], bfr[j][0], acc[2 * P + i2][j], 0, 0, 0);
  }
}

#define READ_AV(P)                                                         \
  av[0][0] = read_frag<NAB>(bufC, 0, wm + (2 * (P)) * 16 + fr, 0, fg);     \
  av[0][1] = read_frag<NAB>(bufC, 0, wm + (2 * (P)) * 16 + fr, 1, fg);     \
  av[1][0] = read_frag<NAB>(bufC, 0, wm + (2 * (P) + 1) * 16 + fr, 0, fg); \
  av[1][1] = read_frag<NAB>(bufC, 0, wm + (2 * (P) + 1) * 16 + fr, 1, fg);

#define PHASE_TAIL(P)                                       \
  __builtin_amdgcn_s_barrier();                             \
  asm volatile("s_waitcnt lgkmcnt(0)" ::: "memory");        \
  __builtin_amdgcn_s_setprio(1);                            \
  mfma_cluster<NAB, P>(acc, av, bfr);                       \
  __builtin_amdgcn_s_setprio(0);                            \
  __builtin_amdgcn_s_barrier();

template <int NAB, bool RELU, int STORE>
__launch_bounds__(512, 2)
__global__ void gemm8_k(unsigned char* wsb,
                        size_t aoff0, size_t aoff1, size_t boff0, size_t boff1,
                        const float* __restrict__ bias,
                        size_t ooff0, size_t ooff1, float* __restrict__ optr,
                        int M, int N, int K, int gx, int gxy) {
  constexpr int BK = (NAB == 2) ? 32 : 64;
  __shared__ alignas(16) short lds[2 * BUF];   // 128 KiB

  unsigned char* ws = wsbase(wsb);
  const int tid = threadIdx.x;
  const int lane = tid & 63;
  const int wave = tid >> 6;
  const int wm = (wave >> 2) << 7;   // 0 / 128
  const int wn = (wave & 3) << 6;    // 0 / 64 / 128 / 192

  // bijective XCD swizzle (all grids are multiples of 8)
  const int nwg = gridDim.x;
  const int q8 = nwg >> 3;
  const int id = (blockIdx.x & 7) * q8 + (blockIdx.x >> 3);
  const int bz = id / gxy;
  const int rem = id - bz * gxy;
  const int by = rem / gx;
  const int bx = rem - by * gx;
  const int brow = by << 8;
  const int bcol = bx << 8;

  const size_t batchA = (size_t)bz * M * K;
  const size_t batchB = (size_t)bz * N * K;
  const short* A0 = (const short*)(ws + aoff0) + batchA;
  const short* A1 = (const short*)(ws + aoff1) + batchA;
  const short* B0g = (const short*)(ws + boff0) + batchB;
  const short* B1g = (const short*)(ws + boff1) + batchB;

  // per-thread staging source offsets (granule-swizzled), [chunk q][half]
  size_t aSrc[2][2], bSrc[2][2];
#pragma unroll
  for (int h = 0; h < 2; ++h) {
    const int G = tid + h * 512;
    if constexpr (NAB == 1) {
      const int r = G >> 3, c = G & 7;
#pragma unroll
      for (int qq = 0; qq < 2; ++qq) {
        aSrc[qq][h] = (size_t)(brow + qq * 128 + r) * K + (size_t)((c ^ (r & 7)) << 3);
        bSrc[qq][h] = (size_t)(bcol + qq * 128 + r) * K + (size_t)((c ^ (r & 7)) << 3);
      }
    } else {
      const int r = G >> 2, c = G & 3;
      const size_t sw = (size_t)((c ^ ((r >> 1) & 3)) << 3);
      aSrc[0][h] = aSrc[1][h] = (size_t)(brow + r) * K + sw;
      bSrc[0][h] = bSrc[1][h] = (size_t)(bcol + r) * K + sw;
    }
  }
  const int ldst0 = tid << 3;   // dest short offset within chunk (16B/lane linear)

  auto issueA = [&](int bsel, int qq, int tt) {
    short* dst = &lds[bsel * BUF + qq * CH];
    const short* sp = (NAB == 2) ? (qq ? A1 : A0) : A0;
    const size_t ka = (size_t)tt * BK;
    gl16(sp + aSrc[qq][0] + ka, dst + ldst0);
    gl16(sp + aSrc[qq][1] + ka, dst + ldst0 + CH / 2);
  };
  auto issueB = [&](int bsel, int qq, int tt) {
    short* dst = &lds[bsel * BUF + (2 + qq) * CH];
    const short* sp = (NAB == 2) ? (qq ? B1g : B0g) : B0g;
    const size_t ka = (size_t)tt * BK;
    gl16(sp + bSrc[qq][0] + ka, dst + ldst0);
    gl16(sp + bSrc[qq][1] + ka, dst + ldst0 + CH / 2);
  };

  const int nt = K / BK;
  const int fr = lane & 15;
  const int fg = lane >> 4;

  f32x4 acc[8][4] = {};

  // prologue: tile0 (A+B) into buf0, B(1) into buf1
  issueA(0, 0, 0); issueA(0, 1, 0);
  issueB(0, 0, 0); issueB(0, 1, 0);
  if (nt > 1) {
    issueB(1, 0, 1); issueB(1, 1, 1);
    asm volatile("s_waitcnt vmcnt(4)" ::: "memory");
  } else {
    asm volatile("s_waitcnt vmcnt(0)" ::: "memory");
  }
  __builtin_amdgcn_s_barrier();

  int cur = 0;
  for (int t = 0; t < nt; ++t) {
    const short* bufC = &lds[cur * BUF];
    const int nx = cur ^ 1;
    short8 av[2][2], bfr[4][2];

    // ---- phase 0: issue A(t+1) chunk0; read B frags + A i=0,1 ----
    if (t + 1 < nt) issueA(nx, 0, t + 1);
#pragma unroll
    for (int j = 0; j < 4; ++j) {
      bfr[j][0] = read_frag<NAB>(bufC, 2 * CH, wn + j * 16 + fr, 0, fg);
      bfr[j][1] = read_frag<NAB>(bufC, 2 * CH, wn + j * 16 + fr, 1, fg);
    }
    READ_AV(0);
    PHASE_TAIL(0);

    // ---- phase 1: issue A(t+1) chunk1; A i=2,3 ----
    if (t + 1 < nt) issueA(nx, 1, t + 1);
    READ_AV(1);
    PHASE_TAIL(1);

    // ---- phase 2: issue B(t+2) chunk0 (B(t) dead after phase 0); A i=4,5 ----
    if (t + 2 < nt) issueB(cur, 0, t + 2);
    READ_AV(2);
    PHASE_TAIL(2);

    // ---- phase 3: issue B(t+2) chunk1; A i=6,7; counted vmcnt ----
    if (t + 2 < nt) issueB(cur, 1, t + 2);
    READ_AV(3);
    if (t + 2 < nt) {
      asm volatile("s_waitcnt vmcnt(4)" ::: "memory");
    } else {
      asm volatile("s_waitcnt vmcnt(0)" ::: "memory");
    }
    PHASE_TAIL(3);

    cur ^= 1;
  }

  // epilogue
  short* Oh = (short*)(ws + ooff0);
  short* Ol = (short*)(ws + ooff1);
  float* Of = (float*)(ws + ooff0) + (size_t)bz * M * N;
  float* Op = optr + (size_t)bz * M * N;
  const int fq4 = (lane >> 4) << 2;
#pragma unroll
  for (int i = 0; i < 8; ++i) {
    const int r = brow + wm + i * 16 + fq4;
#pragma unroll
    for (int j = 0; j < 4; ++j) {
      const int c = bcol + wn + j * 16 + fr;
      const float bv = bias ? bias[c] : 0.0f;
#pragma unroll
      for (int e = 0; e < 4; ++e) {
        float u = acc[i][j][e] + bv;
        if constexpr (RELU) u = fmaxf(u, 0.0f);
        const size_t ro = (size_t)(r + e);
        if constexpr (STORE == 0) {
          const short hb = f2bf(u);
          Oh[ro * N + c] = hb;
          Ol[ro * N + c] = f2bf(u - bf2f(hb));
        } else if constexpr (STORE == 1) {
          Oh[ro * N + c] = f2bf(u);
        } else if constexpr (STORE == 2) {
          Of[(size_t)c * M + ro] = u;   // transposed: ST[n][m]
        } else {
          Op[ro * N + c] = u;
        }
      }
    }
  }
}

// ---------------------------------------------------------------------------
// row softmax over ST rows (axis-1 softmax of scores), output bf16 probs^T
// ---------------------------------------------------------------------------
__launch_bounds__(256)
__global__ void softmax_rows_k(unsigned char* wsb, size_t st, size_t pt) {
  constexpr int S = 2048;
  unsigned char* ws = wsbase(wsb);
  const f32x4* row = (const f32x4*)((const float*)(ws + st) + (size_t)blockIdx.x * S);
  short4v* out = (short4v*)((short*)(ws + pt) + (size_t)blockIdx.x * S);
  const int tid = threadIdx.x, lane = tid & 63, wv = tid >> 6;
  const f32x4 a = row[tid];
  const f32x4 b = row[tid + 256];
  float m = fmaxf(fmaxf(fmaxf(a[0], a[1]), fmaxf(a[2], a[3])),
                  fmaxf(fmaxf(b[0], b[1]), fmaxf(b[2], b[3])));
#pragma unroll
  for (int o = 32; o; o >>= 1) m = fmaxf(m, __shfl_xor(m, o));
  __shared__ float rb[8];
  if (lane == 0) rb[wv] = m;
  __syncthreads();
  m = fmaxf(fmaxf(rb[0], rb[1]), fmaxf(rb[2], rb[3]));
  float e[8];
  float s = 0.0f;
#pragma unroll
  for (int q = 0; q < 4; ++q) { e[q] = expf(a[q] - m); s += e[q]; }
#pragma unroll
  for (int q = 0; q < 4; ++q) { e[4 + q] = expf(b[q] - m); s += e[4 + q]; }
#pragma unroll
  for (int o = 32; o; o >>= 1) s += __shfl_xor(s, o);
  if (lane == 0) rb[4 + wv] = s;
  __syncthreads();
  s = rb[4] + rb[5] + rb[6] + rb[7];
  const float inv = 1.0f / s;
  short4v o1, o2;
#pragma unroll
  for (int q = 0; q < 4; ++q) { o1[q] = f2bf(e[q] * inv); o2[q] = f2bf(e[4 + q] * inv); }
  out[tid] = o1;
  out[tid + 256] = o2;
}

// ---------------------------------------------------------------------------
extern "C" void kernel_launch(void* const* d_in, const int* in_sizes, int n_in,
                              void* d_out, int out_size, void* d_ws, size_t ws_size,
                              hipStream_t stream) {
  const float* x   = (const float*)d_in[0];
  const float* qw1 = (const float*)d_in[1];
  const float* qb1 = (const float*)d_in[2];
  const float* qw2 = (const float*)d_in[3];
  const float* qb2 = (const float*)d_in[4];
  const float* kw1 = (const float*)d_in[5];
  const float* kb1 = (const float*)d_in[6];
  const float* kw2 = (const float*)d_in[7];
  const float* kb2 = (const float*)d_in[8];
  const float* vw1 = (const float*)d_in[9];
  const float* vb1 = (const float*)d_in[10];
  const float* vw2 = (const float*)d_in[11];
  const float* vb2 = (const float*)d_in[12];
  float* out = (float*)d_out;
  unsigned char* wsb = (ws_size >= WS_TOTAL) ? (unsigned char*)d_ws : nullptr;

  const int M = BB * SS;  // 8192
  dim3 blk(512);
  dim3 tb(32, 8);

  // x -> hi/lo bf16
  split_cast_k<<<4096, 256, 0, stream>>>(x, wsb, OFF_XH, OFF_XL, NX / 4);

  // ---- Q path (split precision) ----
  transpose_cast_k<<<dim3(HHID / 32, DD / 32), tb, 0, stream>>>(qw1, wsb, OFF_WH, OFF_WL, DD, HHID, 1);
  gemm8_k<2, true, 0><<<1024, blk, 0, stream>>>(
      wsb, OFF_XH, OFF_XL, OFF_WH, OFF_WL, qb1, OFF_HH, OFF_HL, nullptr, M, HHID, DD, 32, 1024);
  transpose_cast_k<<<dim3(DD / 32, HHID / 32), tb, 0, stream>>>(qw2, wsb, OFF_WH, OFF_WL, HHID, DD, 1);
  gemm8_k<2, false, 0><<<256, blk, 0, stream>>>(
      wsb, OFF_HH, OFF_HL, OFF_WH, OFF_WL, qb2, OFF_QH, OFF_QL, nullptr, M, DD, HHID, 8, 256);

  // ---- K path (split precision) ----
  transpose_cast_k<<<dim3(HHID / 32, DD / 32), tb, 0, stream>>>(kw1, wsb, OFF_WH, OFF_WL, DD, HHID, 1);
  gemm8_k<2, true, 0><<<1024, blk, 0, stream>>>(
      wsb, OFF_XH, OFF_XL, OFF_WH, OFF_WL, kb1, OFF_HH, OFF_HL, nullptr, M, HHID, DD, 32, 1024);
  transpose_cast_k<<<dim3(DD / 32, HHID / 32), tb, 0, stream>>>(kw2, wsb, OFF_WH, OFF_WL, HHID, DD, 1);
  gemm8_k<2, false, 0><<<256, blk, 0, stream>>>(
      wsb, OFF_HH, OFF_HL, OFF_WH, OFF_WL, kb2, OFF_KH, OFF_KL, nullptr, M, DD, HHID, 8, 256);

  // ---- V path (plain bf16) ----
  transpose_cast_k<<<dim3(HHID / 32, DD / 32), tb, 0, stream>>>(vw1, wsb, OFF_WH, OFF_WL, DD, HHID, 0);
  gemm8_k<1, true, 1><<<1024, blk, 0, stream>>>(
      wsb, OFF_XH, 0, OFF_WH, 0, vb1, OFF_HH, 0, nullptr, M, HHID, DD, 32, 1024);
  transpose_cast_k<<<dim3(DD / 32, HHID / 32), tb, 0, stream>>>(vw2, wsb, OFF_WH, OFF_WL, HHID, DD, 0);
  gemm8_k<1, false, 1><<<256, blk, 0, stream>>>(
      wsb, OFF_HH, 0, OFF_WH, 0, vb2, OFF_V, 0, nullptr, M, DD, HHID, 8, 256);

  // ---- scores^T = (Q K^T)^T per batch, split precision, fp32 ----
  gemm8_k<2, false, 2><<<256, blk, 0, stream>>>(
      wsb, OFF_QH, OFF_QL, OFF_KH, OFF_KL, nullptr, OFF_ST, 0, nullptr, SS, SS, DD, 8, 64);

  // ---- softmax over axis 1 == row softmax of ST; writes bf16 probs^T ----
  softmax_rows_k<<<BB * SS, 256, 0, stream>>>(wsb, OFF_ST, OFF_PT);

  // ---- out = V @ probs  (B^T = probs^T), fp32 to d_out ----
  gemm8_k<1, false, 3><<<256, blk, 0, stream>>>(
      wsb, OFF_V, 0, OFF_PT, 0, nullptr, 0, 0, out, SS, SS, DD, 8, 64);
}